// Round 2
// baseline (98.651 us; speedup 1.0000x reference)
//
#include <hip/hip_runtime.h>

// QuanvolutionHybrid: 8192 x 28x28 fp32 images -> 2x2 patches -> 4-qubit circuit
// (Ry encoding, 2 layers of Ry+CNOT ring) -> PauliZ feats [B,784] -> Linear(784,10)
// -> log_softmax. Fully fused, register-resident 16-amplitude state simulation.
//
// Layout: one 64-lane wave per batch row; lane handles patches p = lane+64k.
// wire w <-> bit (3-w) of the 16-amplitude index (matches reference axis order).
// R1 post-mortem: inputs/outputs are fp32 storage (bf16-grade threshold only);
// reading them as bf16 halves produced NaN from random exponent patterns.

template <int BIT>
static __device__ __forceinline__ void apply_ry(float (&a)[16], float c, float s) {
#pragma unroll
    for (int i = 0; i < 16; ++i) {
        if (i & (1 << BIT)) continue;
        float a0 = a[i];
        float a1 = a[i | (1 << BIT)];
        a[i] = c * a0 - s * a1;
        a[i | (1 << BIT)] = s * a0 + c * a1;
    }
}

template <int CBIT, int TBIT>
static __device__ __forceinline__ void apply_cnot(float (&a)[16]) {
#pragma unroll
    for (int i = 0; i < 16; ++i) {
        if ((i & (1 << CBIT)) && !(i & (1 << TBIT))) {
            float t = a[i];
            a[i] = a[i | (1 << TBIT)];
            a[i | (1 << TBIT)] = t;
        }
    }
}

__global__ __launch_bounds__(256) void quanv_fused_kernel(
    const float* __restrict__ x,       // [B,28,28] fp32
    const float* __restrict__ params,  // [2,4] fp32
    const float* __restrict__ W,       // [10,784] fp32
    const float* __restrict__ bias,    // [10] fp32
    float* __restrict__ out,           // [B,10] fp32
    int B)
{
    const int lane = threadIdx.x & 63;
    const int wave = threadIdx.x >> 6;
    const int row  = blockIdx.x * 4 + wave;
    if (row >= B) return;

    // Per-layer Ry cos/sin (shared params, 8 sincos once per thread; L1-hot).
    float lc[2][4], ls[2][4];
#pragma unroll
    for (int l = 0; l < 2; ++l) {
#pragma unroll
        for (int w = 0; w < 4; ++w) {
            float th = 0.5f * params[l * 4 + w];
            __sincosf(th, &ls[l][w], &lc[l][w]);
        }
    }

    float logit[10];
#pragma unroll
    for (int c = 0; c < 10; ++c) logit[c] = 0.0f;

    const float* xrow = x + (size_t)row * 784;

#pragma unroll 1   // keep VGPRs low: each iter already has ~16-wide ILP
    for (int p = lane; p < 196; p += 64) {
        const int i = p / 14;
        const int j = p - i * 14;

        // 2x2 patch: wire0=(2i,2j) wire1=(2i,2j+1) wire2=(2i+1,2j) wire3=(2i+1,2j+1)
        const float* b0 = xrow + (2 * i) * 28 + 2 * j;   // 8B-aligned (even offset)
        float2 r0 = *(const float2*)b0;
        float2 r1 = *(const float2*)(b0 + 28);

        float c0, s0, c1, s1, c2, s2, c3, s3;
        __sincosf(0.5f * r0.x, &s0, &c0);
        __sincosf(0.5f * r0.y, &s1, &c1);
        __sincosf(0.5f * r1.x, &s2, &c2);
        __sincosf(0.5f * r1.y, &s3, &c3);

        // Product state after Ry encoding: amp[idx] = prod_w (bit_w ? s_w : c_w)
        float amp[16];
#pragma unroll
        for (int idx = 0; idx < 16; ++idx) {
            float v = (idx & 8) ? s0 : c0;
            v *= (idx & 4) ? s1 : c1;
            v *= (idx & 2) ? s2 : c2;
            v *= (idx & 1) ? s3 : c3;
            amp[idx] = v;
        }

        // Two variational layers: Ry on each wire, then CNOT ring 0->1->2->3->0.
#pragma unroll
        for (int l = 0; l < 2; ++l) {
            apply_ry<3>(amp, lc[l][0], ls[l][0]);
            apply_ry<2>(amp, lc[l][1], ls[l][1]);
            apply_ry<1>(amp, lc[l][2], ls[l][2]);
            apply_ry<0>(amp, lc[l][3], ls[l][3]);
            apply_cnot<3, 2>(amp);  // ctrl wire0 -> tgt wire1
            apply_cnot<2, 1>(amp);  // ctrl wire1 -> tgt wire2
            apply_cnot<1, 0>(amp);  // ctrl wire2 -> tgt wire3
            apply_cnot<0, 3>(amp);  // ctrl wire3 -> tgt wire0
        }

        // PauliZ expectations per wire.
        float z0 = 0.f, z1 = 0.f, z2 = 0.f, z3 = 0.f;
#pragma unroll
        for (int idx = 0; idx < 16; ++idx) {
            float pq = amp[idx] * amp[idx];
            z0 += (idx & 8) ? -pq : pq;
            z1 += (idx & 4) ? -pq : pq;
            z2 += (idx & 2) ? -pq : pq;
            z3 += (idx & 1) ? -pq : pq;
        }

        // Accumulate logits: W[c, 4p..4p+3] is a 16B-aligned float4; W is L2-hot (31 KB).
        const float* wp = W + 4 * p;
#pragma unroll
        for (int c = 0; c < 10; ++c) {
            float4 wv = *(const float4*)(wp + c * 784);
            logit[c] += z0 * wv.x + z1 * wv.y + z2 * wv.z + z3 * wv.w;
        }
    }

    // Wave-wide butterfly reduction of the 10 partial logits.
#pragma unroll
    for (int off = 32; off > 0; off >>= 1) {
#pragma unroll
        for (int c = 0; c < 10; ++c)
            logit[c] += __shfl_xor(logit[c], off, 64);
    }

    if (lane == 0) {
        float v[10];
        float m = -1e30f;
#pragma unroll
        for (int c = 0; c < 10; ++c) {
            v[c] = logit[c] + bias[c];
            m = fmaxf(m, v[c]);
        }
        float sum = 0.f;
#pragma unroll
        for (int c = 0; c < 10; ++c) sum += __expf(v[c] - m);
        float lse = m + __logf(sum);

        float* o = out + (size_t)row * 10;
#pragma unroll
        for (int c = 0; c < 10; ++c) o[c] = v[c] - lse;
    }
}

extern "C" void kernel_launch(void* const* d_in, const int* in_sizes, int n_in,
                              void* d_out, int out_size, void* d_ws, size_t ws_size,
                              hipStream_t stream) {
    const float* x      = (const float*)d_in[0];
    const float* params = (const float*)d_in[1];
    const float* W      = (const float*)d_in[2];
    const float* bias   = (const float*)d_in[3];
    float* out          = (float*)d_out;

    const int B = in_sizes[0] / 784;          // 8192
    const int blocks = (B + 3) / 4;           // 4 rows (one wave each) per block

    hipLaunchKernelGGL(quanv_fused_kernel, dim3(blocks), dim3(256), 0, stream,
                       x, params, W, bias, out, B);
}

// Round 3
// 86.742 us; speedup vs baseline: 1.1373x; 1.1373x over previous
//
#include <hip/hip_runtime.h>

// QuanvolutionHybrid: 8192 x 28x28 fp32 -> 2x2 patches -> 4-qubit circuit
// (Ry encode, 2x [Ry layer + CNOT ring]) -> PauliZ feats [B,784] -> Linear(784,10)
// -> log_softmax. Fully fused, register-resident 16-amplitude simulation.
//
// R3 changes vs R2 (kernel was ~35-40us, VALU-bound):
//  * layer-0 Ry folded into the encoding product state: Ry(p0)Ry(a)=Ry(a+p0)
//    (no CNOT in between) -> saves 4 of 8 Ry gates (~128 FMA/instr per patch).
//  * 2 rows per wave (32 lanes/row): 7 rounds vs 4 (tail waste 33%->14%),
//    and 2x resident waves (16/CU) for latency hiding.
//  * Z expvals via shared sum tree (76 -> ~56 ops).
// wire w <-> bit (3-w) of the amplitude index.

template <int BIT>
static __device__ __forceinline__ void apply_ry(float (&a)[16], float c, float s) {
#pragma unroll
    for (int i = 0; i < 16; ++i) {
        if (i & (1 << BIT)) continue;
        float a0 = a[i];
        float a1 = a[i | (1 << BIT)];
        a[i] = c * a0 - s * a1;
        a[i | (1 << BIT)] = s * a0 + c * a1;
    }
}

template <int CBIT, int TBIT>
static __device__ __forceinline__ void apply_cnot(float (&a)[16]) {
#pragma unroll
    for (int i = 0; i < 16; ++i) {
        if ((i & (1 << CBIT)) && !(i & (1 << TBIT))) {
            float t = a[i];
            a[i] = a[i | (1 << TBIT)];
            a[i | (1 << TBIT)] = t;
        }
    }
}

__global__ __launch_bounds__(256) void quanv_fused_kernel(
    const float* __restrict__ x,       // [B,28,28]
    const float* __restrict__ params,  // [2,4]
    const float* __restrict__ W,       // [10,784]
    const float* __restrict__ bias,    // [10]
    float* __restrict__ out,           // [B,10]
    int B)
{
    const int lane = threadIdx.x & 63;
    const int lid  = lane & 31;                 // lane within 32-lane row group
    const int wave = threadIdx.x >> 6;
    const int row  = blockIdx.x * 8 + wave * 2 + (lane >> 5);
    if (row >= B) return;

    // Layer-0 half-angles (folded into encoding); layer-1 cos/sin.
    float h0[4], c1w[4], s1w[4];
#pragma unroll
    for (int w = 0; w < 4; ++w) {
        h0[w] = 0.5f * params[w];
        __sincosf(0.5f * params[4 + w], &s1w[w], &c1w[w]);
    }

    float logit[10];
#pragma unroll
    for (int c = 0; c < 10; ++c) logit[c] = 0.0f;

    const float* xrow = x + (size_t)row * 784;

#pragma unroll 1
    for (int p = lid; p < 196; p += 32) {
        const int i = p / 14;
        const int j = p - i * 14;

        // 2x2 patch: wire0=(2i,2j) wire1=(2i,2j+1) wire2=(2i+1,2j) wire3=(2i+1,2j+1)
        const float* b0 = xrow + i * 56 + j * 2;   // 8B-aligned
        float2 r0 = *(const float2*)b0;
        float2 r1 = *(const float2*)(b0 + 28);

        // Encoding Ry(x) fused with layer-0 Ry(p0): half-angle = x/2 + p0/2.
        float c0, s0, c1, s1, c2, s2, c3, s3;
        __sincosf(fmaf(0.5f, r0.x, h0[0]), &s0, &c0);
        __sincosf(fmaf(0.5f, r0.y, h0[1]), &s1, &c1);
        __sincosf(fmaf(0.5f, r1.x, h0[2]), &s2, &c2);
        __sincosf(fmaf(0.5f, r1.y, h0[3]), &s3, &c3);

        // Product state: amp[idx] = p01[idx>>2] * p23[idx&3]  (24 mul total)
        float p01[4] = {c0 * c1, c0 * s1, s0 * c1, s0 * s1};
        float p23[4] = {c2 * c3, c2 * s3, s2 * c3, s2 * s3};
        float amp[16];
#pragma unroll
        for (int idx = 0; idx < 16; ++idx)
            amp[idx] = p01[idx >> 2] * p23[idx & 3];

        // Layer-0 CNOT ring (register renames, free).
        apply_cnot<3, 2>(amp);
        apply_cnot<2, 1>(amp);
        apply_cnot<1, 0>(amp);
        apply_cnot<0, 3>(amp);
        // Layer-1 Ry on each wire.
        apply_ry<3>(amp, c1w[0], s1w[0]);
        apply_ry<2>(amp, c1w[1], s1w[1]);
        apply_ry<1>(amp, c1w[2], s1w[2]);
        apply_ry<0>(amp, c1w[3], s1w[3]);
        // Layer-1 CNOT ring.
        apply_cnot<3, 2>(amp);
        apply_cnot<2, 1>(amp);
        apply_cnot<1, 0>(amp);
        apply_cnot<0, 3>(amp);

        // PauliZ expvals via shared sum tree over probabilities.
        float pr[16];
#pragma unroll
        for (int idx = 0; idx < 16; ++idx) pr[idx] = amp[idx] * amp[idx];

        float sp[8], dp[8];
#pragma unroll
        for (int k = 0; k < 8; ++k) {
            sp[k] = pr[2 * k] + pr[2 * k + 1];
            dp[k] = pr[2 * k] - pr[2 * k + 1];
        }
        float z3 = ((dp[0] + dp[1]) + (dp[2] + dp[3])) + ((dp[4] + dp[5]) + (dp[6] + dp[7]));
        float t[4], u[4];
#pragma unroll
        for (int k = 0; k < 4; ++k) {
            t[k] = sp[2 * k] + sp[2 * k + 1];
            u[k] = sp[2 * k] - sp[2 * k + 1];
        }
        float z2 = (u[0] + u[1]) + (u[2] + u[3]);
        float z1 = (t[0] - t[1]) + (t[2] - t[3]);
        float z0 = (t[0] + t[1]) - (t[2] + t[3]);

        // Logit accumulation: W[c, 4p..4p+3] is a 16B-aligned float4 (L1/L2-hot).
        const float* wp = W + 4 * p;
#pragma unroll
        for (int c = 0; c < 10; ++c) {
            float4 wv = *(const float4*)(wp + c * 784);
            logit[c] = fmaf(z0, wv.x, fmaf(z1, wv.y, fmaf(z2, wv.z, fmaf(z3, wv.w, logit[c]))));
        }
    }

    // Butterfly reduction within each 32-lane row group.
#pragma unroll
    for (int off = 16; off > 0; off >>= 1) {
#pragma unroll
        for (int c = 0; c < 10; ++c)
            logit[c] += __shfl_xor(logit[c], off, 64);
    }

    if (lid == 0) {   // lanes 0 and 32 hold their row's full logits
        float v[10];
        float m = -1e30f;
#pragma unroll
        for (int c = 0; c < 10; ++c) {
            v[c] = logit[c] + bias[c];
            m = fmaxf(m, v[c]);
        }
        float sum = 0.f;
#pragma unroll
        for (int c = 0; c < 10; ++c) sum += __expf(v[c] - m);
        float lse = m + __logf(sum);

        float2* o = (float2*)(out + (size_t)row * 10);   // 40B rows -> 8B aligned
#pragma unroll
        for (int k = 0; k < 5; ++k)
            o[k] = make_float2(v[2 * k] - lse, v[2 * k + 1] - lse);
    }
}

extern "C" void kernel_launch(void* const* d_in, const int* in_sizes, int n_in,
                              void* d_out, int out_size, void* d_ws, size_t ws_size,
                              hipStream_t stream) {
    const float* x      = (const float*)d_in[0];
    const float* params = (const float*)d_in[1];
    const float* W      = (const float*)d_in[2];
    const float* bias   = (const float*)d_in[3];
    float* out          = (float*)d_out;

    const int B = in_sizes[0] / 784;          // 8192
    const int blocks = (B + 7) / 8;           // 8 rows per block (2 per wave)

    hipLaunchKernelGGL(quanv_fused_kernel, dim3(blocks), dim3(256), 0, stream,
                       x, params, W, bias, out, B);
}

// Round 4
// 84.463 us; speedup vs baseline: 1.1680x; 1.0270x over previous
//
#include <hip/hip_runtime.h>

// QuanvolutionHybrid: 8192 x 28x28 fp32 -> 2x2 patches -> 4-qubit circuit
// (Ry encode, 2x [Ry layer + CNOT ring]) -> PauliZ feats [B,784] -> Linear(784,10)
// -> log_softmax. Fully fused, register-resident 16-amplitude simulation.
//
// R4 changes vs R3 (kernel VALU-bound; layer-1 Ry was 47% of body):
//  * tangent-form layer-1 Ry: Ry(th) = c*[[1,-t],[t,1]], t=tan(th/2). Apply the
//    tangent matrix only (2 FMA/pair -> 64 ops vs 128); all amps share scale
//    (prod c_w), so z's share scale2=(prod c)^2, and logits are linear in z ->
//    defer to ONE multiply per row after the wave reduction. Exact algebra.
//  * layer-0 Ry still folded into the encoding sincos (Ry(p0)Ry(a)=Ry(a+p0)).
// wire w <-> bit (3-w) of the amplitude index.

template <int BIT>
static __device__ __forceinline__ void apply_ry_tan(float (&a)[16], float t) {
#pragma unroll
    for (int i = 0; i < 16; ++i) {
        if (i & (1 << BIT)) continue;
        float a0 = a[i];
        float a1 = a[i | (1 << BIT)];
        a[i]              = fmaf(-t, a1, a0);   // a0 - t*a1
        a[i | (1 << BIT)] = fmaf( t, a0, a1);   // a1 + t*a0
    }
}

template <int CBIT, int TBIT>
static __device__ __forceinline__ void apply_cnot(float (&a)[16]) {
#pragma unroll
    for (int i = 0; i < 16; ++i) {
        if ((i & (1 << CBIT)) && !(i & (1 << TBIT))) {
            float t = a[i];
            a[i] = a[i | (1 << TBIT)];
            a[i | (1 << TBIT)] = t;
        }
    }
}

__global__ __launch_bounds__(256) void quanv_fused_kernel(
    const float* __restrict__ x,       // [B,28,28]
    const float* __restrict__ params,  // [2,4]
    const float* __restrict__ W,       // [10,784]
    const float* __restrict__ bias,    // [10]
    float* __restrict__ out,           // [B,10]
    int B)
{
    const int lane = threadIdx.x & 63;
    const int lid  = lane & 31;                 // lane within 32-lane row group
    const int wave = threadIdx.x >> 6;
    const int row  = blockIdx.x * 8 + wave * 2 + (lane >> 5);
    if (row >= B) return;

    // Layer-0 half-angles (folded into encoding); layer-1 tangents + deferred scale.
    float h0[4], t1w[4];
    float scale2 = 1.0f;
#pragma unroll
    for (int w = 0; w < 4; ++w) {
        h0[w] = 0.5f * params[w];
        float s, c;
        __sincosf(0.5f * params[4 + w], &s, &c);
        t1w[w] = s / c;          // tan(theta/2); params fixed, c!=0 in practice
        scale2 *= c;
    }
    scale2 *= scale2;            // (prod_w cos)^2 — applied once per row at the end

    float logit[10];
#pragma unroll
    for (int c = 0; c < 10; ++c) logit[c] = 0.0f;

    const float* xrow = x + (size_t)row * 784;

#pragma unroll 1
    for (int p = lid; p < 196; p += 32) {
        const int i = p / 14;
        const int j = p - i * 14;

        // 2x2 patch: wire0=(2i,2j) wire1=(2i,2j+1) wire2=(2i+1,2j) wire3=(2i+1,2j+1)
        const float* b0 = xrow + i * 56 + j * 2;   // 8B-aligned
        float2 r0 = *(const float2*)b0;
        float2 r1 = *(const float2*)(b0 + 28);

        // Encoding Ry(x) fused with layer-0 Ry(p0): half-angle = x/2 + p0/2.
        float c0, s0, c1, s1, c2, s2, c3, s3;
        __sincosf(fmaf(0.5f, r0.x, h0[0]), &s0, &c0);
        __sincosf(fmaf(0.5f, r0.y, h0[1]), &s1, &c1);
        __sincosf(fmaf(0.5f, r1.x, h0[2]), &s2, &c2);
        __sincosf(fmaf(0.5f, r1.y, h0[3]), &s3, &c3);

        // Product state: amp[idx] = p01[idx>>2] * p23[idx&3]  (24 mul)
        float p01[4] = {c0 * c1, c0 * s1, s0 * c1, s0 * s1};
        float p23[4] = {c2 * c3, c2 * s3, s2 * c3, s2 * s3};
        float amp[16];
#pragma unroll
        for (int idx = 0; idx < 16; ++idx)
            amp[idx] = p01[idx >> 2] * p23[idx & 3];

        // Layer-0 CNOT ring (register renames, free).
        apply_cnot<3, 2>(amp);
        apply_cnot<2, 1>(amp);
        apply_cnot<1, 0>(amp);
        apply_cnot<0, 3>(amp);
        // Layer-1 Ry, tangent form (scale deferred): 2 FMA per pair.
        apply_ry_tan<3>(amp, t1w[0]);
        apply_ry_tan<2>(amp, t1w[1]);
        apply_ry_tan<1>(amp, t1w[2]);
        apply_ry_tan<0>(amp, t1w[3]);
        // Layer-1 CNOT ring (renames).
        apply_cnot<3, 2>(amp);
        apply_cnot<2, 1>(amp);
        apply_cnot<1, 0>(amp);
        apply_cnot<0, 3>(amp);

        // PauliZ expvals (unnormalized by scale2) via shared sum tree.
        float pr[16];
#pragma unroll
        for (int idx = 0; idx < 16; ++idx) pr[idx] = amp[idx] * amp[idx];

        float sp[8], dp[8];
#pragma unroll
        for (int k = 0; k < 8; ++k) {
            sp[k] = pr[2 * k] + pr[2 * k + 1];
            dp[k] = pr[2 * k] - pr[2 * k + 1];
        }
        float z3 = ((dp[0] + dp[1]) + (dp[2] + dp[3])) + ((dp[4] + dp[5]) + (dp[6] + dp[7]));
        float t[4], u[4];
#pragma unroll
        for (int k = 0; k < 4; ++k) {
            t[k] = sp[2 * k] + sp[2 * k + 1];
            u[k] = sp[2 * k] - sp[2 * k + 1];
        }
        float z2 = (u[0] + u[1]) + (u[2] + u[3]);
        float z1 = (t[0] - t[1]) + (t[2] - t[3]);
        float z0 = (t[0] + t[1]) - (t[2] + t[3]);

        // Logit accumulation: W[c, 4p..4p+3] is a 16B-aligned float4 (L1-hot).
        const float* wp = W + 4 * p;
#pragma unroll
        for (int c = 0; c < 10; ++c) {
            float4 wv = *(const float4*)(wp + c * 784);
            logit[c] = fmaf(z0, wv.x, fmaf(z1, wv.y, fmaf(z2, wv.z, fmaf(z3, wv.w, logit[c]))));
        }
    }

    // Butterfly reduction within each 32-lane row group.
#pragma unroll
    for (int off = 16; off > 0; off >>= 1) {
#pragma unroll
        for (int c = 0; c < 10; ++c)
            logit[c] += __shfl_xor(logit[c], off, 64);
    }

    if (lid == 0) {   // lanes 0 and 32 hold their row's full logits
        float v[10];
        float m = -1e30f;
#pragma unroll
        for (int c = 0; c < 10; ++c) {
            v[c] = fmaf(scale2, logit[c], bias[c]);   // deferred tangent-form scale
            m = fmaxf(m, v[c]);
        }
        float sum = 0.f;
#pragma unroll
        for (int c = 0; c < 10; ++c) sum += __expf(v[c] - m);
        float lse = m + __logf(sum);

        float2* o = (float2*)(out + (size_t)row * 10);   // 40B rows -> 8B aligned
#pragma unroll
        for (int k = 0; k < 5; ++k)
            o[k] = make_float2(v[2 * k] - lse, v[2 * k + 1] - lse);
    }
}

extern "C" void kernel_launch(void* const* d_in, const int* in_sizes, int n_in,
                              void* d_out, int out_size, void* d_ws, size_t ws_size,
                              hipStream_t stream) {
    const float* x      = (const float*)d_in[0];
    const float* params = (const float*)d_in[1];
    const float* W      = (const float*)d_in[2];
    const float* bias   = (const float*)d_in[3];
    float* out          = (float*)d_out;

    const int B = in_sizes[0] / 784;          // 8192
    const int blocks = (B + 7) / 8;           // 8 rows per block (2 per wave)

    hipLaunchKernelGGL(quanv_fused_kernel, dim3(blocks), dim3(256), 0, stream,
                       x, params, W, bias, out, B);
}

// Round 5
// 83.241 us; speedup vs baseline: 1.1851x; 1.0147x over previous
//
#include <hip/hip_runtime.h>

// QuanvolutionHybrid: 8192 x 28x28 fp32 -> 2x2 patches -> 4-qubit circuit
// (Ry encode, 2x [Ry layer + CNOT ring]) -> PauliZ feats [B,784] -> Linear(784,10)
// -> log_softmax. Fully fused, register-resident 16-amplitude simulation.
//
// R5 change vs R4: stage W (31.4 KB) in LDS. R4 post-mortem showed the kernel is
// L1-BW bound on the 10x float4 W loads per patch (~8.0us L1-pipe vs ~4.7us VALU);
// LDS is ~2x wider and the two 32-lane row-groups read identical addresses
// (broadcast, free). VALU becomes the bound again (~5-6us kernel).
// Carried: layer-0 Ry folded into encoding sincos; layer-1 in tangent form with
// the (prod cos)^2 scale deferred to one fmaf per row. wire w <-> bit (3-w).

template <int BIT>
static __device__ __forceinline__ void apply_ry_tan(float (&a)[16], float t) {
#pragma unroll
    for (int i = 0; i < 16; ++i) {
        if (i & (1 << BIT)) continue;
        float a0 = a[i];
        float a1 = a[i | (1 << BIT)];
        a[i]              = fmaf(-t, a1, a0);   // a0 - t*a1
        a[i | (1 << BIT)] = fmaf( t, a0, a1);   // a1 + t*a0
    }
}

template <int CBIT, int TBIT>
static __device__ __forceinline__ void apply_cnot(float (&a)[16]) {
#pragma unroll
    for (int i = 0; i < 16; ++i) {
        if ((i & (1 << CBIT)) && !(i & (1 << TBIT))) {
            float t = a[i];
            a[i] = a[i | (1 << TBIT)];
            a[i | (1 << TBIT)] = t;
        }
    }
}

__global__ __launch_bounds__(256) void quanv_fused_kernel(
    const float* __restrict__ x,       // [B,28,28]
    const float* __restrict__ params,  // [2,4]
    const float* __restrict__ W,       // [10,784]
    const float* __restrict__ bias,    // [10]
    float* __restrict__ out,           // [B,10]
    int B)
{
    __shared__ float Wl[10 * 784];     // 31360 B; 5 blocks/CU still fit

    // Cooperative W staging: 1960 float4s over 256 threads (8 rounds, coalesced).
    {
        const float4* Wg4 = (const float4*)W;
        float4* Wl4 = (float4*)Wl;
#pragma unroll
        for (int t = threadIdx.x; t < 1960; t += 256) Wl4[t] = Wg4[t];
    }
    __syncthreads();   // before any row guard: all threads must reach this

    const int lane = threadIdx.x & 63;
    const int lid  = lane & 31;                 // lane within 32-lane row group
    const int wave = threadIdx.x >> 6;
    const int row  = blockIdx.x * 8 + wave * 2 + (lane >> 5);
    if (row >= B) return;

    // Layer-0 half-angles (folded into encoding); layer-1 tangents + deferred scale.
    float h0[4], t1w[4];
    float scale2 = 1.0f;
#pragma unroll
    for (int w = 0; w < 4; ++w) {
        h0[w] = 0.5f * params[w];
        float s, c;
        __sincosf(0.5f * params[4 + w], &s, &c);
        t1w[w] = s / c;          // tan(theta/2); params fixed, |c| not tiny in practice
        scale2 *= c;
    }
    scale2 *= scale2;            // (prod_w cos)^2 — applied once per row at the end

    float logit[10];
#pragma unroll
    for (int c = 0; c < 10; ++c) logit[c] = 0.0f;

    const float* xrow = x + (size_t)row * 784;

#pragma unroll 1
    for (int p = lid; p < 196; p += 32) {
        const int i = p / 14;
        const int j = p - i * 14;

        // 2x2 patch: wire0=(2i,2j) wire1=(2i,2j+1) wire2=(2i+1,2j) wire3=(2i+1,2j+1)
        const float* b0 = xrow + i * 56 + j * 2;   // 8B-aligned
        float2 r0 = *(const float2*)b0;
        float2 r1 = *(const float2*)(b0 + 28);

        // Encoding Ry(x) fused with layer-0 Ry(p0): half-angle = x/2 + p0/2.
        float c0, s0, c1, s1, c2, s2, c3, s3;
        __sincosf(fmaf(0.5f, r0.x, h0[0]), &s0, &c0);
        __sincosf(fmaf(0.5f, r0.y, h0[1]), &s1, &c1);
        __sincosf(fmaf(0.5f, r1.x, h0[2]), &s2, &c2);
        __sincosf(fmaf(0.5f, r1.y, h0[3]), &s3, &c3);

        // Product state: amp[idx] = p01[idx>>2] * p23[idx&3]  (24 mul)
        float p01[4] = {c0 * c1, c0 * s1, s0 * c1, s0 * s1};
        float p23[4] = {c2 * c3, c2 * s3, s2 * c3, s2 * s3};
        float amp[16];
#pragma unroll
        for (int idx = 0; idx < 16; ++idx)
            amp[idx] = p01[idx >> 2] * p23[idx & 3];

        // Layer-0 CNOT ring (register renames, free).
        apply_cnot<3, 2>(amp);
        apply_cnot<2, 1>(amp);
        apply_cnot<1, 0>(amp);
        apply_cnot<0, 3>(amp);
        // Layer-1 Ry, tangent form (scale deferred): 2 FMA per pair.
        apply_ry_tan<3>(amp, t1w[0]);
        apply_ry_tan<2>(amp, t1w[1]);
        apply_ry_tan<1>(amp, t1w[2]);
        apply_ry_tan<0>(amp, t1w[3]);
        // Layer-1 CNOT ring (renames).
        apply_cnot<3, 2>(amp);
        apply_cnot<2, 1>(amp);
        apply_cnot<1, 0>(amp);
        apply_cnot<0, 3>(amp);

        // PauliZ expvals (unnormalized by scale2) via shared sum tree.
        float pr[16];
#pragma unroll
        for (int idx = 0; idx < 16; ++idx) pr[idx] = amp[idx] * amp[idx];

        float sp[8], dp[8];
#pragma unroll
        for (int k = 0; k < 8; ++k) {
            sp[k] = pr[2 * k] + pr[2 * k + 1];
            dp[k] = pr[2 * k] - pr[2 * k + 1];
        }
        float z3 = ((dp[0] + dp[1]) + (dp[2] + dp[3])) + ((dp[4] + dp[5]) + (dp[6] + dp[7]));
        float t[4], u[4];
#pragma unroll
        for (int k = 0; k < 4; ++k) {
            t[k] = sp[2 * k] + sp[2 * k + 1];
            u[k] = sp[2 * k] - sp[2 * k + 1];
        }
        float z2 = (u[0] + u[1]) + (u[2] + u[3]);
        float z1 = (t[0] - t[1]) + (t[2] - t[3]);
        float z0 = (t[0] + t[1]) - (t[2] + t[3]);

        // Logit accumulation from LDS: lanes stride 16B (contiguous 512B per group,
        // both 32-lane groups read the SAME addresses -> broadcast, conflict-free).
        const float* wp = Wl + 4 * p;
#pragma unroll
        for (int c = 0; c < 10; ++c) {
            float4 wv = *(const float4*)(wp + c * 784);
            logit[c] = fmaf(z0, wv.x, fmaf(z1, wv.y, fmaf(z2, wv.z, fmaf(z3, wv.w, logit[c]))));
        }
    }

    // Butterfly reduction within each 32-lane row group.
#pragma unroll
    for (int off = 16; off > 0; off >>= 1) {
#pragma unroll
        for (int c = 0; c < 10; ++c)
            logit[c] += __shfl_xor(logit[c], off, 64);
    }

    if (lid == 0) {   // lanes 0 and 32 hold their row's full logits
        float v[10];
        float m = -1e30f;
#pragma unroll
        for (int c = 0; c < 10; ++c) {
            v[c] = fmaf(scale2, logit[c], bias[c]);   // deferred tangent-form scale
            m = fmaxf(m, v[c]);
        }
        float sum = 0.f;
#pragma unroll
        for (int c = 0; c < 10; ++c) sum += __expf(v[c] - m);
        float lse = m + __logf(sum);

        float2* o = (float2*)(out + (size_t)row * 10);   // 40B rows -> 8B aligned
#pragma unroll
        for (int k = 0; k < 5; ++k)
            o[k] = make_float2(v[2 * k] - lse, v[2 * k + 1] - lse);
    }
}

extern "C" void kernel_launch(void* const* d_in, const int* in_sizes, int n_in,
                              void* d_out, int out_size, void* d_ws, size_t ws_size,
                              hipStream_t stream) {
    const float* x      = (const float*)d_in[0];
    const float* params = (const float*)d_in[1];
    const float* W      = (const float*)d_in[2];
    const float* bias   = (const float*)d_in[3];
    float* out          = (float*)d_out;

    const int B = in_sizes[0] / 784;          // 8192
    const int blocks = (B + 7) / 8;           // 8 rows per block (2 per wave)

    hipLaunchKernelGGL(quanv_fused_kernel, dim3(blocks), dim3(256), 0, stream,
                       x, params, W, bias, out, B);
}